// Round 11
// baseline (269.996 us; speedup 1.0000x reference)
//
#include <hip/hip_runtime.h>

#define EMB 2048
#define UDIM 256
#define KTOT 2304
#define NE 64
#define TOPK 8
#define SSH 6144              // shorts per k-step in wb (12288 B)
#define STEPB 12288           // bytes per k-step
#define KSPL 8                // K-split factor
#define SPS 9                 // k-steps per slice (72/8)
#define SLICEB (SPS * STEPB)  // 110592 B LDS slice
#define NB 64                 // tile-group blocks per slice (grid = 512)
#define NTOK 16384
#define PART_OFF (1 << 20)    // partial buffer offset in workspace (bytes)

typedef __attribute__((ext_vector_type(8))) short short8;
typedef __attribute__((ext_vector_type(4))) float f32x4;
typedef __attribute__((ext_vector_type(4))) unsigned int u32x4;

__device__ __forceinline__ unsigned short bf16h(float x) {
  unsigned uu = __builtin_bit_cast(unsigned, x);
  return (unsigned short)((uu + 0x7FFFu + ((uu >> 16) & 1u)) >> 16);
}
__device__ __forceinline__ float bf2f(unsigned short s) {
  return __builtin_bit_cast(float, ((unsigned)s) << 16);
}

// packed RNE f32x2 -> bf16x2
__device__ __forceinline__ unsigned cvtpk(float a, float b) {
  unsigned r;
  asm("v_cvt_pk_bf16_f32 %0, %1, %2" : "=v"(r) : "v"(a), "v"(b));
  return r;
}

// ---- prep: W fp32 [2304][64] -> triple-split bf16 in MFMA-FRAGMENT order ----
// wb[kstep][plane][nt][lane][j]:  lane = (kk>>3)*16 + (n&15), j = kk&7
__global__ __launch_bounds__(256)
void prep_w(const float* __restrict__ W, unsigned short* __restrict__ wb) {
  const int flat = blockIdx.x * 256 + threadIdx.x;  // 0..147455
  const int k = flat >> 6;
  const int n = flat & 63;
  const float w = W[flat];
  const unsigned short h0 = bf16h(w);
  const float r1 = w - bf2f(h0);   // exact in fp32
  const unsigned short h1 = bf16h(r1);
  const float r2 = r1 - bf2f(h1);  // exact in fp32
  const unsigned short h2 = bf16h(r2);

  const int s = k >> 5;
  const int kk = k & 31;
  const int lane = (kk >> 3) * 16 + (n & 15);
  const int j = kk & 7;
  const int nt = n >> 4;
  const size_t base = (size_t)s * SSH + ((size_t)nt * 64 + lane) * 8 + j;
  wb[base] = h0;
  wb[base + 2048] = h1;
  wb[base + 4096] = h2;
}

// per-step math for ONE tile: triple-split convert of 8 fp32 + 24 MFMAs
__device__ __forceinline__ void step_math(const f32x4& c0, const f32x4& c1,
                                          const short8* Bv, f32x4* acc) {
  const float xs[8] = {c0[0], c0[1], c0[2], c0[3],
                       c1[0], c1[1], c1[2], c1[3]};
  u32x4 W0, W1, W2;
#pragma unroll
  for (int k2 = 0; k2 < 4; ++k2) {
    const float a = xs[2 * k2], bbv = xs[2 * k2 + 1];
    const unsigned p0 = cvtpk(a, bbv);
    const float a1 = a - __builtin_bit_cast(float, p0 << 16);
    const float b1 = bbv - __builtin_bit_cast(float, p0 & 0xFFFF0000u);
    const unsigned p1 = cvtpk(a1, b1);
    const float a2 = a1 - __builtin_bit_cast(float, p1 << 16);
    const float b2 = b1 - __builtin_bit_cast(float, p1 & 0xFFFF0000u);
    const unsigned p2 = cvtpk(a2, b2);
    W0[k2] = p0; W1[k2] = p1; W2[k2] = p2;
  }
  const short8 A0 = __builtin_bit_cast(short8, W0);
  const short8 A1 = __builtin_bit_cast(short8, W1);
  const short8 A2 = __builtin_bit_cast(short8, W2);

#pragma unroll
  for (int nt = 0; nt < 4; ++nt) {
    acc[nt] = __builtin_amdgcn_mfma_f32_16x16x32_bf16(A0, Bv[0 + nt], acc[nt], 0, 0, 0);
    acc[nt] = __builtin_amdgcn_mfma_f32_16x16x32_bf16(A0, Bv[4 + nt], acc[nt], 0, 0, 0);
    acc[nt] = __builtin_amdgcn_mfma_f32_16x16x32_bf16(A1, Bv[0 + nt], acc[nt], 0, 0, 0);
    acc[nt] = __builtin_amdgcn_mfma_f32_16x16x32_bf16(A1, Bv[4 + nt], acc[nt], 0, 0, 0);
    acc[nt] = __builtin_amdgcn_mfma_f32_16x16x32_bf16(A0, Bv[8 + nt], acc[nt], 0, 0, 0);
    acc[nt] = __builtin_amdgcn_mfma_f32_16x16x32_bf16(A2, Bv[0 + nt], acc[nt], 0, 0, 0);
  }
}

// ---- split-K GEMM: B-stationary LDS, dual-tile waves (plain loads) ----
// Grid = 8 K-slices x 64 blocks (512). Block stages its 108 KB wb-slice
// once; 8 waves each compute 2 token-tiles SIMULTANEOUSLY over 288 k:
// per step 12 ds_read_b128 feed 48 MFMA (2 tiles) -> per-token LDS traffic
// halved, and tile-1's dep-free math hides tile-0's LDS/convert latency
// in-wave. A uses PLAIN loads: compiler-managed waits are spill-safe
// (R10 lesson: asm-pinned 36-load burst spills -> corrupts vmcnt AND data).
__global__ __launch_bounds__(512, 1)
void gate_split(const float* __restrict__ h, const float* __restrict__ u,
                const unsigned short* __restrict__ wb,
                float* __restrict__ partial) {
  __shared__ __align__(1024) char lds[SLICEB];  // 108 KB

  const int tid = threadIdx.x;
  const int lane = tid & 63;
  const int wid = __builtin_amdgcn_readfirstlane(tid >> 6);  // 0..7
  const int kq = blockIdx.x >> 6;   // K slice 0..7
  const int bb = blockIdx.x & 63;   // tile-group
  const int mm = lane & 15;         // A: token-in-tile | B: expert%16
  const int q8 = (lane >> 4) * 8;   // k-subgroup within frag

  // ---- stage wb slice (identity byte-map; LDS dest wave-uniform) ----
  const char* src = (const char*)wb + (size_t)kq * SLICEB + (size_t)lane * 16;
  for (int j = wid; j < SPS * 12; j += 8)  // 108 chunks of 1024 B
    __builtin_amdgcn_global_load_lds(
        (const __attribute__((address_space(1))) unsigned int*)(src + (size_t)j * 1024),
        (__attribute__((address_space(3))) unsigned int*)(lds + (size_t)j * 1024),
        16, 0, 0);
  __syncthreads();  // one-time drain; main body below has no barriers

  const bool tail = (kq == KSPL - 1);
  const char* lb = lds + (size_t)lane * 16;
  const int ks0 = kq * SPS;
  const int tb = (bb * 8 + wid) * 2;  // 2 tiles per wave

  const int tok0 = (tb + 0) * 16 + mm;
  const int tok1 = (tb + 1) * 16 + mm;
  const float* hr0 = h + (size_t)tok0 * EMB + q8;
  const float* ur0 = u + (size_t)tok0 * UDIM + q8;
  const float* hr1 = h + (size_t)tok1 * EMB + q8;
  const float* ur1 = u + (size_t)tok1 * UDIM + q8;

  f32x4 acc0[4], acc1[4];
#pragma unroll
  for (int nt = 0; nt < 4; ++nt) { acc0[nt] = 0.f; acc1[nt] = 0.f; }

  // both tiles' A slices, plain loads (compiler schedules + inserts waits)
  f32x4 Aa[2 * SPS], Ab[2 * SPS];
#pragma unroll
  for (int s = 0; s < SPS; ++s) {
    const float* p0;
    const float* p1;
    if (!tail) {
      p0 = hr0 + (ks0 + s) * 32;
      p1 = hr1 + (ks0 + s) * 32;
    } else {
      p0 = (s == 0) ? (hr0 + 2016) : (ur0 + (s - 1) * 32);
      p1 = (s == 0) ? (hr1 + 2016) : (ur1 + (s - 1) * 32);
    }
    Aa[2 * s] = *(const f32x4*)p0;
    Aa[2 * s + 1] = *(const f32x4*)(p0 + 4);
    Ab[2 * s] = *(const f32x4*)p1;
    Ab[2 * s + 1] = *(const f32x4*)(p1 + 4);
  }

#pragma unroll
  for (int s = 0; s < SPS; ++s) {
    short8 Bv[12];
#pragma unroll
    for (int q = 0; q < 12; ++q)
      Bv[q] = *(const short8*)(lb + (size_t)s * STEPB + q * 1024);
    step_math(Aa[2 * s], Aa[2 * s + 1], Bv, acc0);
    step_math(Ab[2 * s], Ab[2 * s + 1], Bv, acc1);
  }

  // ---- write both partial tiles: D row=(lane>>4)*4+r, col=nt*16+mm ----
  const int rowb = (lane >> 4) * 4;
#pragma unroll
  for (int nt = 0; nt < 4; ++nt)
#pragma unroll
    for (int r = 0; r < 4; ++r) {
      partial[((size_t)kq * NTOK + (tb + 0) * 16 + rowb + r) * NE + nt * 16 + mm] =
          acc0[nt][r];
      partial[((size_t)kq * NTOK + (tb + 1) * 16 + rowb + r) * NE + nt * 16 + mm] =
          acc1[nt][r];
    }
}

// ---- finalize: reduce 8 partials + bias + softmax + top-8, 1 token/wave ----
__global__ __launch_bounds__(256)
void finalize(const float* __restrict__ partial, const float* __restrict__ b,
              float* __restrict__ out) {
  const int tid = threadIdx.x;
  const int lane = tid & 63;
  const int wv = tid >> 6;  // 0..3
  const int t = blockIdx.x * 4 + wv;  // token
  const float bias = b[lane];

  float g = bias;
#pragma unroll
  for (int s = 0; s < KSPL; ++s)
    g += partial[((size_t)s * NTOK + t) * NE + lane];

  float m = g;
#pragma unroll
  for (int off = 32; off > 0; off >>= 1)
    m = fmaxf(m, __shfl_xor(m, off));
  float pexp = __expf(g - m);
  float sum = pexp;
#pragma unroll
  for (int off = 32; off > 0; off >>= 1)
    sum += __shfl_xor(sum, off);
  const float pn = pexp / sum;

  float vv = pn;
  float topsum = 0.f;
  int sel = 0;
  for (int r = 0; r < TOPK; ++r) {
    float mv = vv;
    int mi = lane;
#pragma unroll
    for (int off = 32; off > 0; off >>= 1) {
      const float ov = __shfl_xor(mv, off);
      const int oi = __shfl_xor(mi, off);
      if (ov > mv || (ov == mv && oi < mi)) { mv = ov; mi = oi; }
    }
    topsum += mv;
    if (lane == mi) { sel = 1; vv = -1.f; }
  }

  out[(size_t)t * NE + lane] = sel ? pn / (topsum + 1e-9f) : 0.f;
}

extern "C" void kernel_launch(void* const* d_in, const int* in_sizes, int n_in,
                              void* d_out, int out_size, void* d_ws, size_t ws_size,
                              hipStream_t stream) {
  const float* h = (const float*)d_in[0];
  const float* u = (const float*)d_in[1];
  const float* W = (const float*)d_in[2];
  const float* b = (const float*)d_in[3];
  float* out = (float*)d_out;

  unsigned short* wb = (unsigned short*)d_ws;           // 884736 B
  float* partial = (float*)((char*)d_ws + PART_OFF);    // 8*16384*64*4 = 33.5 MB

  hipLaunchKernelGGL(prep_w, dim3(KTOT * NE / 256), dim3(256), 0, stream, W, wb);
  hipLaunchKernelGGL(gate_split, dim3(KSPL * NB), dim3(512), 0, stream,
                     h, u, wb, partial);
  hipLaunchKernelGGL(finalize, dim3(NTOK / 4), dim3(256), 0, stream,
                     partial, b, out);
}